// Round 3
// baseline (110.667 us; speedup 1.0000x reference)
//
#include <hip/hip_runtime.h>

#define F_   512
#define FF_  (512 * 512)
#define C_   128

typedef __attribute__((ext_vector_type(4))) float f32x4;
typedef __attribute__((ext_vector_type(8))) short s16x8;
typedef __attribute__((ext_vector_type(4))) unsigned short u16x4;

__device__ __forceinline__ unsigned short f2bf(float f) {
    union { float f; unsigned u; } v; v.f = f;
    unsigned r = v.u + 0x7fffu + ((v.u >> 16) & 1u);   // RNE
    return (unsigned short)(r >> 16);
}

__device__ __forceinline__ s16x8 pack8(f32x4 lo, f32x4 hi) {
    s16x8 r;
    r[0] = (short)f2bf(lo[0]); r[1] = (short)f2bf(lo[1]);
    r[2] = (short)f2bf(lo[2]); r[3] = (short)f2bf(lo[3]);
    r[4] = (short)f2bf(hi[0]); r[5] = (short)f2bf(hi[1]);
    r[6] = (short)f2bf(hi[2]); r[7] = (short)f2bf(hi[3]);
    return r;
}

#define GLDS16(gp, lp)                                                         \
    __builtin_amdgcn_global_load_lds(                                          \
        (const __attribute__((address_space(1))) void*)(gp),                   \
        (__attribute__((address_space(3))) void*)(lp), 16, 0, 0)

// ---------------------------------------------------------------------------
// Kernel 1 v3: params = phi @ Wc^T (+bc), mask, -> wT[b][k][i] bf16 + bias.
// Direct global->register B-fragments (no LDS staging, no barriers in the
// main loop, waves independent). Per-lane exec-masked loads skip masked
// (i,k) rows exactly (50.8% keep => ~68 MB fetch). LDS used only for the
// output transpose. Blocks 0..2047: 16i x 8k tiles. Blocks 2048+: bias.
// ---------------------------------------------------------------------------
__global__ __launch_bounds__(256, 4) void k1_params(
    const float* __restrict__ phi, const float* __restrict__ Wc,
    const float* __restrict__ bc, unsigned short* __restrict__ wT,
    float* __restrict__ biasWS)
{
    const int blk = blockIdx.x;
    const int tid = threadIdx.x;

    if (blk >= 2048) {                      // ---- bias part ----
        int g = ((blk - 2048) << 8) + tid;  // 0..32767
        int k = g >> 6, b = g & 63;         // 64 lanes share one Wc row
        const f32x4* w4 = (const f32x4*)(Wc + (size_t)(FF_ + k) * C_);
        const f32x4* p4 = (const f32x4*)(phi + b * C_);
        float acc = bc[FF_ + k];
#pragma unroll
        for (int c = 0; c < 32; ++c) {
            f32x4 a = w4[c], q = p4[c];
            acc += a[0]*q[0] + a[1]*q[1] + a[2]*q[2] + a[3]*q[3];
        }
        biasWS[(b << 9) + k] = acc;
        return;
    }

    __shared__ __align__(16) unsigned short trans[64 * 192];   // 24.6 KB

    const int lane = tid & 63, wave = tid >> 6, quad = lane >> 4;
    const int i0 = (blk >> 6) << 4;     // 32 i-tiles of 16
    const int k0 = (blk & 63) << 3;     // 64 k-tiles of 8

    // hoist phi A-frags for this wave's 16-b m-tile (16 VGPRs)
    s16x8 afr[4];
    {
        const int brow = (wave << 4) + (lane & 15);
        const float* p0 = phi + brow * C_ + (quad << 3);
#pragma unroll
        for (int kk = 0; kk < 4; ++kk)
            afr[kk] = pack8(*(const f32x4*)(p0 + kk * 32),
                            *(const f32x4*)(p0 + kk * 32 + 4));
    }

    // per-lane cell coords: D col = lane&15 -> (di, kq)
    const int c16 = lane & 15;
    const int di  = c16 >> 3, kq = c16 & 7;
    const int kcur = k0 + kq;
    const int dk   = kcur % 63;

    // per-ct keep bits + bias values
    unsigned keepm = 0;
    float bcv[8];
#pragma unroll
    for (int ct = 0; ct < 8; ++ct) {
        int icur = i0 + ct * 2 + di;
        if ((icur % 63) >= dk) keepm |= 1u << ct;
        bcv[ct] = bc[icur * F_ + kcur];
    }

    const float* wbase = Wc + (size_t)((i0 + di) * F_ + kcur) * C_ + (quad << 3);

#pragma unroll
    for (int ct = 0; ct < 8; ++ct) {
        const float* wrow = wbase + (size_t)ct * (2 * F_ * C_);
        const bool keep = (keepm >> ct) & 1;
        f32x4 lo[4], hi[4];
        if (keep) {
#pragma unroll
            for (int kk = 0; kk < 4; ++kk) {
                lo[kk] = *(const f32x4*)(wrow + kk * 32);
                hi[kk] = *(const f32x4*)(wrow + kk * 32 + 4);
            }
        } else {
#pragma unroll
            for (int kk = 0; kk < 4; ++kk) {
                lo[kk] = (f32x4){0.f, 0.f, 0.f, 0.f};
                hi[kk] = (f32x4){0.f, 0.f, 0.f, 0.f};
            }
        }
        f32x4 acc = (f32x4){0.f, 0.f, 0.f, 0.f};
#pragma unroll
        for (int kk = 0; kk < 4; ++kk)
            acc = __builtin_amdgcn_mfma_f32_16x16x32_bf16(
                afr[kk], pack8(lo[kk], hi[kk]), acc, 0, 0, 0);

        const float bv = bcv[ct];
        const int   ii = ct * 2 + di;
#pragma unroll
        for (int r = 0; r < 4; ++r) {
            int b = (wave << 4) + (quad << 2) + r;
            trans[b * 192 + kq * 24 + ii] =
                keep ? f2bf(acc[r] + bv) : (unsigned short)0;
        }
    }
    __syncthreads();

    // store: 64 b x 8 k x 16 i bf16 -> wT, coalesced 16B chunks
#pragma unroll
    for (int j = 0; j < 4; ++j) {
        int q = (j << 8) + tid;            // 0..1023
        int b = q >> 4, kq2 = (q >> 1) & 7, h = q & 1;
        s16x8 v = *(const s16x8*)&trans[b * 192 + kq2 * 24 + (h << 3)];
        *(s16x8*)&wT[(((size_t)((b << 9) + k0 + kq2)) << 9) + i0 + (h << 3)] = v;
    }
}

// ---------------------------------------------------------------------------
// Kernel 2 (unchanged): per (b, 64-row tile): two chained GEMMs vs wT + bias,
// residual epilogue. ~15 us, near its BW floor.
// ---------------------------------------------------------------------------
#define SMEM_BOFF 66560           // 64*1040
#define CHUNK_B   32768
#define SMEM_TOT  (66560 + 2 * 32768)   // 132096

__global__ __launch_bounds__(512) void k2_apply(
    const float* __restrict__ X, const unsigned short* __restrict__ wT,
    const float* __restrict__ biasWS, float* __restrict__ out)
{
    extern __shared__ char smem[];
    unsigned short* A_lds = (unsigned short*)smem;

    const int blk = blockIdx.x;
    const int sw  = ((blk & 7) << 5) + (blk >> 3);   // XCD swizzle
    const int b   = sw >> 2;
    const int n0  = (sw & 3) << 6;

    const int tid = threadIdx.x, lane = tid & 63, wave = tid >> 6;
    const int wn = wave >> 2, wk = wave & 3;

    const float* Xb = X + (((size_t)(b * 256 + n0)) << 9);
    float*       Ob = out + (((size_t)(b * 256 + n0)) << 9);
    const unsigned short* wTb = wT + ((size_t)b << 18);

    float biasr[8];
#pragma unroll
    for (int nt = 0; nt < 8; ++nt)
        biasr[nt] = biasWS[(b << 9) + (wk << 7) + (nt << 4) + (lane & 15)];

    // stage relu(X) -> A_lds bf16
    {
        const f32x4* X4 = (const f32x4*)Xb;
#pragma unroll
        for (int j = 0; j < 16; ++j) {
            int f = (j << 9) + tid;
            int row = f >> 7, c4 = f & 127;
            f32x4 v = X4[f];
            u16x4 h;
#pragma unroll
            for (int e = 0; e < 4; ++e) h[e] = f2bf(fmaxf(v[e], 0.f));
            *(u16x4*)&A_lds[row * 520 + (c4 << 2)] = h;
        }
    }

    const int srcslot = ((lane & 3) ^ ((lane >> 3) & 3)) << 3;

    f32x4 acc[2][8];

    for (int phase = 0; phase < 2; ++phase) {
#pragma unroll
        for (int mt = 0; mt < 2; ++mt)
#pragma unroll
            for (int nt = 0; nt < 8; ++nt) acc[mt][nt] = (f32x4){0.f, 0.f, 0.f, 0.f};

#pragma unroll
        for (int g = 0; g < 4; ++g) {
            int krow = (wave << 6) + (g << 4) + (lane >> 2);
            const unsigned short* src = wTb + ((size_t)krow << 9) + srcslot;
            char* lp = smem + SMEM_BOFF + (((wave << 6) + (g << 4)) << 6);
            GLDS16(src, lp);
        }
        asm volatile("s_waitcnt vmcnt(0)" ::: "memory");
        __syncthreads();

        for (int c = 0; c < 16; ++c) {
            const int cur = c & 1;
            if (c < 15) {
                const int i0n = (c + 1) << 5;
#pragma unroll
                for (int g = 0; g < 4; ++g) {
                    int krow = (wave << 6) + (g << 4) + (lane >> 2);
                    const unsigned short* src = wTb + ((size_t)krow << 9) + i0n + srcslot;
                    char* lp = smem + SMEM_BOFF + (cur ^ 1) * CHUNK_B
                             + (((wave << 6) + (g << 4)) << 6);
                    GLDS16(src, lp);
                }
            }
            const int i0c = c << 5;
            s16x8 afr[2];
#pragma unroll
            for (int mt = 0; mt < 2; ++mt) {
                int n = (wn << 5) + (mt << 4) + (lane & 15);
                afr[mt] = *(const s16x8*)&A_lds[n * 520 + i0c + ((lane >> 4) << 3)];
            }
            const unsigned short* Bb =
                (const unsigned short*)(smem + SMEM_BOFF + cur * CHUNK_B);
#pragma unroll
            for (int nt = 0; nt < 8; ++nt) {
                int k = (wk << 7) + (nt << 4) + (lane & 15);
                int slot = (((lane >> 4) ^ ((k >> 1) & 3)) << 3);
                s16x8 bfr = *(const s16x8*)&Bb[(k << 5) + slot];
#pragma unroll
                for (int mt = 0; mt < 2; ++mt)
                    acc[mt][nt] = __builtin_amdgcn_mfma_f32_16x16x32_bf16(
                        afr[mt], bfr, acc[mt][nt], 0, 0, 0);
            }
            asm volatile("s_waitcnt vmcnt(0)" ::: "memory");
            __syncthreads();
        }

        if (phase == 0) {
#pragma unroll
            for (int mt = 0; mt < 2; ++mt)
#pragma unroll
                for (int nt = 0; nt < 8; ++nt) {
                    int k = (wk << 7) + (nt << 4) + (lane & 15);
#pragma unroll
                    for (int r = 0; r < 4; ++r) {
                        int n = (wn << 5) + (mt << 4) + ((lane >> 4) << 2) + r;
                        A_lds[n * 520 + k] =
                            f2bf(fmaxf(acc[mt][nt][r] + biasr[nt], 0.f));
                    }
                }
            __syncthreads();
        }
    }

#pragma unroll
    for (int mt = 0; mt < 2; ++mt)
#pragma unroll
        for (int nt = 0; nt < 8; ++nt) {
            int k = (wk << 7) + (nt << 4) + (lane & 15);
#pragma unroll
            for (int r = 0; r < 4; ++r) {
                int n = (wn << 5) + (mt << 4) + ((lane >> 4) << 2) + r;
                size_t off = ((size_t)n << 9) + k;
                Ob[off] = Xb[off] + acc[mt][nt][r] + biasr[nt];
            }
        }
}

extern "C" void kernel_launch(void* const* d_in, const int* in_sizes, int n_in,
                              void* d_out, int out_size, void* d_ws, size_t ws_size,
                              hipStream_t stream) {
    const float* inputs = (const float*)d_in[0];
    const float* phi    = (const float*)d_in[1];
    const float* Wc     = (const float*)d_in[2];
    const float* bc     = (const float*)d_in[3];
    float* out = (float*)d_out;

    unsigned short* wT = (unsigned short*)d_ws;                         // 32 MiB
    float* biasWS = (float*)((char*)d_ws + (size_t)64 * 512 * 512 * 2); // 64*512 fp32

    hipLaunchKernelGGL(k1_params, dim3(2176), dim3(256), 0, stream,
                       phi, Wc, bc, wT, biasWS);

    hipFuncSetAttribute((const void*)k2_apply,
                        hipFuncAttributeMaxDynamicSharedMemorySize, SMEM_TOT);
    hipLaunchKernelGGL(k2_apply, dim3(256), dim3(512), SMEM_TOT, stream,
                       inputs, wT, biasWS, out);
}